// Round 15
// baseline (220.746 us; speedup 1.0000x reference)
//
#include <hip/hip_runtime.h>

#define BINS 10
#define TPB  256
#define NB_MAX 2048
#define KPACK 16384.0f
#define LN2f   0.69314718055994531f
#define LOG2Ef 1.44269504088896f

// Single fused kernel (round 15).
// Main loop: EXACT R14 structure (naive guarded grid-stride, register loads,
// direct consumption) -- the R13 ablation proved the compiler + 32-wave TLP
// schedule this better than every hand pipeline (rotation/LDS-queue/asm
// vmcnt all 1.4x-2x slower). Math: threshold-prefix binning, native
// exp2/log, (count,sum) fused per element via +KPACK.
// Epilogue: 20 fire-and-forget global atomicAdds per block -> last-block
// ticket -> in-kernel finalize. Removes the second dispatch (~3 us) at the
// cost of an 84-byte memset dispatch.
__global__ __launch_bounds__(TPB, 4) void ghmc_fused_kernel(
    const float4* __restrict__ pred4,
    const int4*   __restrict__ tgt4,
    const int4*   __restrict__ lw4,
    float* __restrict__ gacc,    // [20]: 0..9 prefix-S2, 10..19 prefix-count
    int*   __restrict__ ticket,  // arrival counter
    float* __restrict__ out,
    int n4, int n, int nb)
{
    float A[BINS];
#pragma unroll
    for (int b = 0; b < BINS; ++b) A[b] = 0.f;

    const float Q[9] = {-2.19722458f, -1.38629436f, -0.84729786f,
                        -0.40546511f,  0.0f,         0.40546511f,
                         0.84729786f,  1.38629436f,  2.19722458f};

    auto proc = [&](float p, int t, int w) {
        // q = t ? -p : p;  bin from thresholds on q;  bce = softplus(q)
        float q    = __int_as_float(__float_as_int(p) ^ (int)((unsigned)t << 31));
        float e    = __builtin_amdgcn_exp2f(fabsf(q) * -LOG2Ef);   // e^-|q|
        float d    = 1.f + e;
        float bce2 = fmaf(fmaxf(q, 0.f), LOG2Ef,
                          __builtin_amdgcn_logf(d));               // softplus/ln2
        float v    = (w > 0) ? (bce2 + KPACK) : 0.f;
        A[0] += v;
#pragma unroll
        for (int k = 0; k < 9; ++k)
            A[k + 1] += (q >= Q[k]) ? v : 0.f;   // bin >= k+1  <=>  q >= Q[k]
    };

    const int tid    = threadIdx.x;
    const int stride = gridDim.x * TPB;
    const int base   = blockIdx.x * TPB + tid;
    const int full   = n4 / stride;

    // naive guarded loop; extra iteration covers the remainder quad
    for (int k = 0; k <= full; ++k) {
        const int i = base + k * stride;
        if (i < n4) {
            float4 p = pred4[i];
            int4   t = tgt4[i];
            int4   w = lw4[i];
            proc(p.x, t.x, w.x); proc(p.y, t.y, w.y);
            proc(p.z, t.z, w.z); proc(p.w, t.w, w.w);
        }
    }
    // scalar tail (n not divisible by 4; cold at bench shape)
    if (blockIdx.x == 0 && tid < (n & 3)) {
        const float* predf = (const float*)pred4;
        const int*   tgtf  = (const int*)tgt4;
        const int*   lwf   = (const int*)lw4;
        const int j = n4 * 4 + tid;
        proc(predf[j], tgtf[j], lwf[j]);
    }

    // 4-level xor reduce of the 10 fused prefix accumulators
    // (16-lane group total <= 16*20*16407 ~ 5.3M < 2^24: count part exact)
#pragma unroll
    for (int b = 0; b < BINS; ++b) {
#pragma unroll
        for (int off = 1; off <= 8; off <<= 1)
            A[b] += __shfl_xor(A[b], off, 64);
    }

    // 16 group leaders separate prefix count / prefix sum
    __shared__ float red[2 * BINS][16];   // 1.28 KB
    const int grp = tid >> 4;
    if ((tid & 15) == 0) {
#pragma unroll
        for (int b = 0; b < BINS; ++b) {
            float Cf = floorf(A[b] * (1.f / KPACK));
            red[b][grp]        = A[b] - KPACK * Cf;   // prefix S2 (log2 scale)
            red[BINS + b][grp] = Cf;                  // prefix count
        }
    }
    __syncthreads();
    // 20 threads -> fire-and-forget device-scope atomics (no return, no wait)
    if (tid < 2 * BINS) {
        float v = 0.f;
#pragma unroll
        for (int g = 0; g < 16; ++g) v += red[tid][g];
        atomicAdd(&gacc[tid], v);
    }

    // last-block-done: fence own writes, sync, then one arrival per block
    __threadfence();
    __syncthreads();
    __shared__ int lastFlag;
    if (tid == 0) {
        int old = atomicAdd(ticket, 1);
        lastFlag = (old == nb - 1);
    }
    __syncthreads();
    if (!lastFlag) return;

    // final scalar, computed by one thread of the last-arriving block
    if (tid == 0) {
        __threadfence();
        float PS2[BINS + 1], PC[BINS + 1];
        PS2[BINS] = 0.f; PC[BINS] = 0.f;
#pragma unroll
        for (int b = 0; b < BINS; ++b) {
            // agent-scope atomic loads: bypass possibly-stale per-XCD L2
            PS2[b] = __hip_atomic_load(&gacc[b],        __ATOMIC_RELAXED,
                                       __HIP_MEMORY_SCOPE_AGENT);
            PC[b]  = __hip_atomic_load(&gacc[BINS + b], __ATOMIC_RELAXED,
                                       __HIP_MEMORY_SCOPE_AGENT);
        }
        float ti  = PC[0];            // total valid = prefix count at level 0
        int   nbn = 0;
        float cnts[BINS], sums[BINS];
#pragma unroll
        for (int b = 0; b < BINS; ++b) {
            cnts[b] = PC[b]  - PC[b + 1];    // exact integer diff
            sums[b] = PS2[b] - PS2[b + 1];
            nbn += (cnts[b] > 0.5f) ? 1 : 0;
        }
        float total = fmaxf(ti, 1.f);
        float nf    = (float)(nbn > 0 ? nbn : 1);
        float loss  = 0.f;
#pragma unroll
        for (int b = 0; b < BINS; ++b) {
            if (cnts[b] > 0.5f) {
                float w = (total / cnts[b]) / nf;     // w_bin[b]
                loss += w * (sums[b] * LN2f);         // S = S2 * ln2
            }
        }
        out[0] = loss / total * 1.0f;  // LOSS_WEIGHT = 1.0
    }
}

extern "C" void kernel_launch(void* const* d_in, const int* in_sizes, int n_in,
                              void* d_out, int out_size, void* d_ws, size_t ws_size,
                              hipStream_t stream)
{
    const float4* pred4 = (const float4*)d_in[0];
    const int4*   tgt4  = (const int4*)d_in[1];
    const int4*   lw4   = (const int4*)d_in[2];

    const int n  = in_sizes[0];
    const int n4 = n / 4;

    int nb = (n4 + TPB - 1) / TPB;
    if (nb > NB_MAX) nb = NB_MAX;
    if (nb < 1) nb = 1;

    float* gacc   = (float*)d_ws;                       // 20 floats
    int*   ticket = (int*)((char*)d_ws + 20 * sizeof(float));

    // zero accumulators + ticket (ticket MUST be 0: ws is poisoned 0xAA once)
    hipMemsetAsync(d_ws, 0, 21 * sizeof(float), stream);

    ghmc_fused_kernel<<<nb, TPB, 0, stream>>>(pred4, tgt4, lw4,
                                              gacc, ticket, (float*)d_out,
                                              n4, n, nb);
}

// Round 16
// 35.674 us; speedup vs baseline: 6.1879x; 6.1879x over previous
//
#include <hip/hip_runtime.h>

#define BINS 10
#define TPB  256
#define NB_MAX 2048
#define FTPB 1024   // finalize block size
#define KPACK 16384.0f
#define LN2f   0.69314718055994531f
#define LOG2Ef 1.44269504088896f

// Pass 1 (round 16): R14 structure verbatim -- naive guarded grid-stride
// loop, register loads, direct consumption (R13 ablation: the compiler +
// TLP beat every hand pipeline). ONE change: __launch_bounds__(256, 8).
// R14's kernel needs only 20 VGPRs, so the 64-VGPR cap of (256,8) is not
// binding (R5's spill disaster came from a ~70-VGPR kernel under the same
// cap). 32 waves/CU doubles loads-in-flight -> read-MLP (Little's law)
// and halves the launch ramp tail.
// Math: threshold-prefix binning (bin = sum_k (q >= logit(k/10))), native
// exp2/log, (count,sum) fused per element via +KPACK; prefixes un-diffed
// in the finalize kernel.
__global__ __launch_bounds__(TPB, 8) void ghmc_hist_kernel(
    const float4* __restrict__ pred4,
    const int4*   __restrict__ tgt4,
    const int4*   __restrict__ lw4,
    float* __restrict__ part,      // [nb][2*BINS]
    int n4, int n)
{
    float A[BINS];
#pragma unroll
    for (int b = 0; b < BINS; ++b) A[b] = 0.f;

    const float Q[9] = {-2.19722458f, -1.38629436f, -0.84729786f,
                        -0.40546511f,  0.0f,         0.40546511f,
                         0.84729786f,  1.38629436f,  2.19722458f};

    auto proc = [&](float p, int t, int w) {
        // q = t ? -p : p;  bin from thresholds on q;  bce = softplus(q)
        float q    = __int_as_float(__float_as_int(p) ^ (int)((unsigned)t << 31));
        float e    = __builtin_amdgcn_exp2f(fabsf(q) * -LOG2Ef);   // e^-|q|
        float d    = 1.f + e;
        float bce2 = fmaf(fmaxf(q, 0.f), LOG2Ef,
                          __builtin_amdgcn_logf(d));               // softplus/ln2
        float v    = (w > 0) ? (bce2 + KPACK) : 0.f;
        A[0] += v;
#pragma unroll
        for (int k = 0; k < 9; ++k)
            A[k + 1] += (q >= Q[k]) ? v : 0.f;   // bin >= k+1  <=>  q >= Q[k]
    };

    const int tid    = threadIdx.x;
    const int stride = gridDim.x * TPB;
    const int base   = blockIdx.x * TPB + tid;
    const int full   = n4 / stride;

    // naive guarded loop, one extra iteration covers the remainder quad
    for (int k = 0; k <= full; ++k) {
        const int i = base + k * stride;
        if (i < n4) {
            float4 p = pred4[i];
            int4   t = tgt4[i];
            int4   w = lw4[i];
            proc(p.x, t.x, w.x); proc(p.y, t.y, w.y);
            proc(p.z, t.z, w.z); proc(p.w, t.w, w.w);
        }
    }
    // scalar tail (n not divisible by 4; cold at bench shape)
    if (blockIdx.x == 0 && tid < (n & 3)) {
        const float* predf = (const float*)pred4;
        const int*   tgtf  = (const int*)tgt4;
        const int*   lwf   = (const int*)lw4;
        const int j = n4 * 4 + tid;
        proc(predf[j], tgtf[j], lwf[j]);
    }

    // 4-level xor reduce of the 10 fused prefix accumulators
    // (16-lane group total <= 16*20*16407 ~ 5.3M < 2^24: count part exact)
#pragma unroll
    for (int b = 0; b < BINS; ++b) {
#pragma unroll
        for (int off = 1; off <= 8; off <<= 1)
            A[b] += __shfl_xor(A[b], off, 64);
    }

    // 16 group leaders separate prefix count / prefix sum; 20 threads write
    __shared__ float red[2 * BINS][16];   // 1.28 KB
    const int grp = tid >> 4;
    if ((tid & 15) == 0) {
#pragma unroll
        for (int b = 0; b < BINS; ++b) {
            float Cf = floorf(A[b] * (1.f / KPACK));
            red[b][grp]        = A[b] - KPACK * Cf;   // prefix S2 (log2 scale)
            red[BINS + b][grp] = Cf;                  // prefix count
        }
    }
    __syncthreads();
    if (tid < 2 * BINS) {
        float v = 0.f;
#pragma unroll
        for (int g = 0; g < 16; ++g) v += red[tid][g];
        part[blockIdx.x * (2 * BINS) + tid] = v;   // contiguous record
    }
}

// Pass 2: reduce nb 20-float records (rows 0..9 prefix-S2, 10..19 prefix-C),
// un-diff the prefixes, compute the scalar loss (S = S2 * ln2).
__global__ __launch_bounds__(FTPB) void ghmc_final_kernel(
    const float* __restrict__ part, float* __restrict__ out, int nb)
{
    float acc[2 * BINS];
#pragma unroll
    for (int v = 0; v < 2 * BINS; ++v) acc[v] = 0.f;

    const int tid = threadIdx.x;
    for (int i = tid; i < nb; i += FTPB) {
        const float4* rec = (const float4*)(part + (size_t)i * (2 * BINS));
        float4 a = rec[0], b = rec[1], c = rec[2], d = rec[3], e = rec[4];
        acc[0]  += a.x; acc[1]  += a.y; acc[2]  += a.z; acc[3]  += a.w;
        acc[4]  += b.x; acc[5]  += b.y; acc[6]  += b.z; acc[7]  += b.w;
        acc[8]  += c.x; acc[9]  += c.y; acc[10] += c.z; acc[11] += c.w;
        acc[12] += d.x; acc[13] += d.y; acc[14] += d.z; acc[15] += d.w;
        acc[16] += e.x; acc[17] += e.y; acc[18] += e.z; acc[19] += e.w;
    }

#pragma unroll
    for (int v = 0; v < 2 * BINS; ++v) {
#pragma unroll
        for (int off = 1; off <= 32; off <<= 1)
            acc[v] += __shfl_xor(acc[v], off, 64);
    }

    __shared__ float sh[2 * BINS][16];
    const int wv = tid >> 6, lane = tid & 63;
    if (lane == 0) {
#pragma unroll
        for (int v = 0; v < 2 * BINS; ++v) sh[v][wv] = acc[v];
    }
    __syncthreads();
    if (tid < 2 * BINS) {
        float s = 0.f;
#pragma unroll
        for (int g = 0; g < 16; ++g) s += sh[tid][g];
        sh[tid][0] = s;
    }
    __syncthreads();

    if (tid == 0) {
        float PS2[BINS + 1], PC[BINS + 1];
        PS2[BINS] = 0.f; PC[BINS] = 0.f;
#pragma unroll
        for (int b = 0; b < BINS; ++b) { PS2[b] = sh[b][0]; PC[b] = sh[BINS + b][0]; }

        float ti = PC[0];          // total valid = prefix count at level 0
        int nbn = 0;
        float cnts[BINS], sums[BINS];
#pragma unroll
        for (int b = 0; b < BINS; ++b) {
            cnts[b] = PC[b]  - PC[b + 1];    // exact integer diff
            sums[b] = PS2[b] - PS2[b + 1];
            nbn += (cnts[b] > 0.5f) ? 1 : 0;
        }
        float total = fmaxf(ti, 1.f);
        float nf    = (float)(nbn > 0 ? nbn : 1);
        float loss  = 0.f;
#pragma unroll
        for (int b = 0; b < BINS; ++b) {
            if (cnts[b] > 0.5f) {
                float w = (total / cnts[b]) / nf;     // w_bin[b]
                loss += w * (sums[b] * LN2f);         // S = S2 * ln2
            }
        }
        out[0] = loss / total * 1.0f;  // LOSS_WEIGHT = 1.0
    }
}

extern "C" void kernel_launch(void* const* d_in, const int* in_sizes, int n_in,
                              void* d_out, int out_size, void* d_ws, size_t ws_size,
                              hipStream_t stream)
{
    const float4* pred4 = (const float4*)d_in[0];
    const int4*   tgt4  = (const int4*)d_in[1];
    const int4*   lw4   = (const int4*)d_in[2];

    const int n  = in_sizes[0];
    const int n4 = n / 4;

    int nb = (n4 + TPB - 1) / TPB;
    if (nb > NB_MAX) nb = NB_MAX;
    int ws_cap = (int)(ws_size / (2 * BINS * sizeof(float)));
    if (nb > ws_cap) nb = ws_cap;
    if (nb < 1) nb = 1;

    float* part = (float*)d_ws;   // [nb][2*BINS]

    ghmc_hist_kernel<<<nb, TPB, 0, stream>>>(pred4, tgt4, lw4, part, n4, n);
    ghmc_final_kernel<<<1, FTPB, 0, stream>>>(part, (float*)d_out, nb);
}